// Round 1
// 903.071 us; speedup vs baseline: 1.0251x; 1.0251x over previous
//
#include <hip/hip_runtime.h>

// ChannelGroupConv: 1x1 grouped-causal conv == block-triangular 128x128 GEMM
// over 4*512*512 pixels. Memory-bound (1.07 GB floor ~= 170 us @ 6.3 TB/s).
//
// v2 vs v1: fix the global access pattern (was 4 B/lane scalar dword both ways).
//  - MFMA operands SWAPPED: D = x_tile * w  -> lane holds D[px=4q+r][co=l16],
//    so stores are direct float4 (16 B/lane), no epilogue LDS.
//  - Loads: each wave reads a 256-px span of one channel as float4 (1 KiB/instr
//    fully coalesced), converts to bf16, LDS-transposes; A-fragments then come
//    from single ds_read_b128 (8 contiguous ci at one pixel).
//  - LDS layout [ci>>3][px][ci&7] bf16, XOR-swizzled byte ^= ((px>>2)&7)<<4 to
//    break write-side bank conflicts (write addr proven bijective).

#define HW     (512 * 512)       // 2^18 pixels per channel plane
#define TPX    256               // pixels per block tile
#define NTILES (4 * HW / TPX)    // 4096

typedef __attribute__((ext_vector_type(8))) short bf16x8;  // 8 bf16 = 4 VGPRs
typedef __attribute__((ext_vector_type(4))) float f32x4;

// round-to-nearest-even; rounded bf16 sits in the HIGH 16 bits of the result
__device__ inline unsigned rne32(float f) {
    unsigned u = __float_as_uint(f);
    return u + 0x7FFFu + ((u >> 16) & 1u);
}

__global__ __launch_bounds__(256, 2)
void cgc_mfma_kernel(const float* __restrict__ x, const float* __restrict__ w,
                     const float* __restrict__ bias, float* __restrict__ out,
                     int ntiles) {
    // bf16 X[128 ci][256 px] as [rb=ci>>3][px][ci&7]:
    //   byte(ci,px) = ((( (ci>>3)*TPX + px ) << 4) + (ci&7)*2) ^ (((px>>2)&7)<<4)
    __shared__ unsigned char lds[TPX * 128 * 2];   // 64 KiB -> 2 blocks/CU

    const int tid  = threadIdx.x;
    const int lane = tid & 63;
    const int wv   = tid >> 6;     // wave 0..3
    const int quad = lane >> 4;    // 0..3
    const int l16  = lane & 15;

    // ---- weight fragments (now the B operand; data layout unchanged from v1):
    // lane holds W[co=16t+l16][ci=32kk+8*quad+j], masked block-triangular.
    bf16x8 wfrag[8][4];
    #pragma unroll
    for (int t = 0; t < 8; ++t) {
        const int co   = 16 * t + l16;
        const int klim = (co & ~7) + 8;            // causal: ci < klim kept
        #pragma unroll
        for (int kk = 0; kk <= t / 2; ++kk) {      // triangular: 20 fragments
            const int k0 = 32 * kk + quad * 8;
            const float* wp = w + co * 128 + k0;
            bf16x8 f;
            #pragma unroll
            for (int j = 0; j < 8; ++j) {
                float v = (k0 < klim) ? wp[j] : 0.0f;
                f[j] = (short)(rne32(v) >> 16);
            }
            wfrag[t][kk] = f;
        }
    }

    // bias now lives on the l16 (=co) axis of D: one scalar per t
    float biasv[8];
    #pragma unroll
    for (int t = 0; t < 8; ++t) biasv[t] = bias[16 * t + l16];

    for (int tile = blockIdx.x; tile < ntiles; tile += gridDim.x) {
        const int b      = tile >> 10;             // tile / (HW/TPX)
        const int pxbase = (tile & 1023) << 8;     // tile-local pixel base
        const size_t xoff = ((size_t)(b * 128) << 18) + (size_t)pxbase;

        __syncthreads();   // previous tile's LDS reads complete

        // ---- stage: 16 iters, channel pair (8i+2wv, +1), px = 4*lane+d ----
        {
            const float* pbase = x + xoff + 4 * lane;
            #pragma unroll 4
            for (int i = 0; i < 16; ++i) {
                const int ci0 = 8 * i + 2 * wv;             // even, rb = i
                const float* pa = pbase + ((size_t)ci0 << 18);
                f32x4 A = *(const f32x4*)pa;                // 1 KiB coalesced
                f32x4 B = *(const f32x4*)(pa + (1 << 18));  // 1 KiB coalesced
                #pragma unroll
                for (int d = 0; d < 4; ++d) {
                    // pack bf16(ci0) lo | bf16(ci0+1) hi
                    unsigned pk = (rne32(B[d]) & 0xFFFF0000u) | (rne32(A[d]) >> 16);
                    const int px   = 4 * lane + d;
                    const int byte = ((((i * TPX + px) << 4) + 4 * wv)
                                     ^ (((px >> 2) & 7) << 4));
                    *(unsigned*)(lds + byte) = pk;          // ds_write_b32
                }
            }
        }
        __syncthreads();

        // ---- compute: wave owns px [64*wv, 64*wv+64), 4 subtiles of 16 ----
        #pragma unroll
        for (int s = 0; s < 4; ++s) {
            const int p0 = 64 * wv + 16 * s;
            const int px = p0 + l16;

            // A fragments: lane holds x[px][ci=32kk+8*quad+j] -> one b128 each
            bf16x8 xf[4];
            #pragma unroll
            for (int kk = 0; kk < 4; ++kk) {
                const int byte = ((((4 * kk + quad) * TPX + px) << 4)
                                 ^ (((px >> 2) & 7) << 4));
                xf[kk] = *(const bf16x8*)(lds + byte);      // ds_read_b128
            }

            f32x4 acc[8];
            #pragma unroll
            for (int t = 0; t < 8; ++t) {
                f32x4 a; a[0] = a[1] = a[2] = a[3] = biasv[t];
                acc[t] = a;
            }
            #pragma unroll
            for (int kk = 0; kk < 4; ++kk)
                #pragma unroll
                for (int t = 2 * kk; t < 8; ++t)            // triangular: 20 MFMAs
                    acc[t] = __builtin_amdgcn_mfma_f32_16x16x32_bf16(
                        xf[kk], wfrag[t][kk], acc[t], 0, 0, 0);

            // D[row=px-p0=4*quad+r][col=co=16t+l16]: 4 consecutive px of one co
            #pragma unroll
            for (int t = 0; t < 8; ++t) {
                float* op = out + xoff + ((size_t)(16 * t + l16) << 18)
                            + p0 + 4 * quad;
                *(f32x4*)op = acc[t];                       // global_store_dwordx4
            }
        }
    }
}

extern "C" void kernel_launch(void* const* d_in, const int* in_sizes, int n_in,
                              void* d_out, int out_size, void* d_ws, size_t ws_size,
                              hipStream_t stream) {
    const float* x    = (const float*)d_in[0];
    const float* w    = (const float*)d_in[1];
    const float* bias = (const float*)d_in[2];
    float* out        = (float*)d_out;

    // 512 blocks = 2 resident blocks/CU (64 KiB LDS each); 4096/512 = 8 tiles each
    dim3 grid(512), block(256);
    hipLaunchKernelGGL(cgc_mfma_kernel, grid, block, 0, stream,
                       x, w, bias, out, NTILES);
}